// Round 11
// baseline (438.574 us; speedup 1.0000x reference)
//
#include <hip/hip_runtime.h>
#include <hip/hip_bf16.h>
#include <stdint.h>

#define DD 512
#define HW 9216
#define NBATCH 8
#define BN_EPS 1e-5f

typedef __attribute__((ext_vector_type(8))) short short8;
typedef __attribute__((ext_vector_type(4))) float f32x4;

__device__ __forceinline__ unsigned short f2bf(float f) {
  union { float f; uint32_t u; } v; v.f = f;
  uint32_t r = v.u + 0x7FFFu + ((v.u >> 16) & 1u);   // RNE
  return (unsigned short)(r >> 16);
}
__device__ __forceinline__ uint64_t pack4bf(float y0, float y1, float y2, float y3) {
  return (uint64_t)f2bf(y0) | ((uint64_t)f2bf(y1) << 16) |
         ((uint64_t)f2bf(y2) << 32) | ((uint64_t)f2bf(y3) << 48);
}

// ---------------- prep: bf16 weights + folded BN ----------------
__global__ void prep_kernel(const float* __restrict__ W1, const float* __restrict__ W2,
                            const float* __restrict__ s1, const float* __restrict__ b1,
                            const float* __restrict__ m1, const float* __restrict__ v1,
                            const float* __restrict__ s2, const float* __restrict__ b2,
                            const float* __restrict__ m2, const float* __restrict__ v2,
                            unsigned short* __restrict__ W1b, unsigned short* __restrict__ W2b,
                            float* __restrict__ sc1, float* __restrict__ sh1,
                            float* __restrict__ sc2, float* __restrict__ sh2) {
  int t = blockIdx.x * 256 + threadIdx.x;
  if (t < DD * DD) { W1b[t] = f2bf(W1[t]); W2b[t] = f2bf(W2[t]); }
  if (t < DD) {
    float a = s1[t] * rsqrtf(v1[t] + BN_EPS);
    sc1[t] = a; sh1[t] = b1[t] - m1[t] * a;
    float c = s2[t] * rsqrtf(v2[t] + BN_EPS);
    sc2[t] = c; sh2[t] = b2[t] - m2[t] * c;
  }
}

// prep codebooks: CWt[112][512] (transposed concat), CWc[512][128] (native concat, 0-pad)
__global__ void prep_cw(const float* __restrict__ cw1, const float* __restrict__ cw2,
                        const float* __restrict__ cw3,
                        unsigned short* __restrict__ CWt, unsigned short* __restrict__ CWc) {
  int t = blockIdx.x * 256 + threadIdx.x;   // 65536 total
  int d = t >> 7, k = t & 127;
  float v = 0.f;
  if (k < 16) v = cw1[d * 16 + k];
  else if (k < 48) v = cw2[d * 32 + (k - 16)];
  else if (k < 112) v = cw3[d * 64 + (k - 48)];
  unsigned short bv = f2bf(v);
  CWc[d * 128 + k] = bv;
  if (k < 112) CWt[k * 512 + d] = bv;
}

// ------- GEMM + BN + ReLU; output TRANSPOSED Yt[n][e] bf16 -------
// MODE 0: input X fp32 [d][n] (scalar-gather B-stage) + fused cb1 logits+softmax
//         -> P1p[n][16] (blockIdx.y==0 blocks only; d is the K dim, fully in-block).
// MODE 1: input X2t bf16 [n][e] (b128 B-stage).
template <int MODE>
__global__ __launch_bounds__(256) void gemm_bn(
    const void* __restrict__ Xin_, const unsigned short* __restrict__ Wb,
    const float* __restrict__ scale, const float* __restrict__ shift,
    const unsigned short* __restrict__ CWt, const float* __restrict__ gg1,
    unsigned short* __restrict__ Yt, unsigned short* __restrict__ P1p) {
  const int b  = blockIdx.z;
  const int e0 = blockIdx.y * 128;
  const int n0 = blockIdx.x * 128;
  const int tid  = threadIdx.x;
  const int lane = tid & 63;
  const int wave = tid >> 6;
  const int wr = wave >> 1, wc = wave & 1;
  const size_t bHW = (size_t)b * HW;

  constexpr int BSTR = (MODE == 0) ? 40 : 32;
  __shared__ __align__(16) unsigned short Alds[128 * 32];
  __shared__ __align__(16) unsigned short Blds[128 * BSTR];

  const float* Xf           = (const float*)Xin_ + bHW * DD;          // MODE 0
  const unsigned short* Xt  = (const unsigned short*)Xin_;            // MODE 1: [g][512]

  f32x4 acc[4][4];
#pragma unroll
  for (int i = 0; i < 4; i++)
#pragma unroll
    for (int j = 0; j < 4; j++) acc[i][j] = (f32x4)0.0f;

  f32x4 accP[2];             // cb1 logits (MODE 0, y==0 only)
  accP[0] = (f32x4)0.0f; accP[1] = (f32x4)0.0f;

  const int arow  = tid >> 1;
  const int ahalf = tid & 1;
  const int bcol  = tid & 127;
  const int bdh   = tid >> 7;

  const int koff = (lane >> 4) * 8;
  const int lrow = lane & 15;

  for (int kt = 0; kt < DD / 32; ++kt) {
    const int d0 = kt * 32;
    __syncthreads();
    {  // stage A: W rows (bf16, contiguous)
      const unsigned short* src = Wb + (size_t)(e0 + arow) * DD + d0 + ahalf * 16;
      short8 v0 = *(const short8*)(src);
      short8 v1 = *(const short8*)(src + 8);
      *(short8*)&Alds[arow * 32 + ahalf * 16]     = v0;
      *(short8*)&Alds[arow * 32 + ahalf * 16 + 8] = v1;
    }
    if (MODE == 0) {  // stage B: transpose-gather X fp32 [d][n] -> Blds[n][k]
      unsigned short* dst = &Blds[bcol * 40 + bdh * 16];
      const float* src = Xf + (size_t)(d0 + bdh * 16) * HW + n0 + bcol;
#pragma unroll
      for (int j = 0; j < 8; j++) {
        uint32_t u0 = f2bf(src[(size_t)(2 * j) * HW]);
        uint32_t u1 = f2bf(src[(size_t)(2 * j + 1) * HW]);
        *(uint32_t*)&dst[2 * j] = u0 | (u1 << 16);
      }
    } else {          // stage B: b128 rows from X2t [g][512]
      const int row = tid >> 1, half = tid & 1;
      short8 v = *(const short8*)&Xt[(bHW + n0 + row) * 512 + d0 + half * 16];
      *(short8*)&Blds[row * 32 + half * 16] = v;
    }
    __syncthreads();

    short8 af[4], bfr[4];
#pragma unroll
    for (int ma = 0; ma < 4; ma++)
      af[ma] = *(const short8*)&Alds[(wr * 64 + ma * 16 + lrow) * 32 + koff];
#pragma unroll
    for (int nb = 0; nb < 4; nb++)
      bfr[nb] = *(const short8*)&Blds[(wc * 64 + nb * 16 + lrow) * BSTR + koff];
#pragma unroll
    for (int ma = 0; ma < 4; ma++)
#pragma unroll
      for (int nb = 0; nb < 4; nb++)
        acc[ma][nb] = __builtin_amdgcn_mfma_f32_16x16x32_bf16(af[ma], bfr[nb], acc[ma][nb], 0, 0, 0);

    if (MODE == 0 && blockIdx.y == 0) {
      // cb1 logits: A = CWt rows 0..15 (codes), B = this wave's 2 pos-tiles.
      short8 a1f = *(const short8*)&CWt[(size_t)lrow * 512 + d0 + koff];
      short8 bp0 = *(const short8*)&Blds[(wave * 32 + lrow) * 40 + koff];
      short8 bp1 = *(const short8*)&Blds[(wave * 32 + 16 + lrow) * 40 + koff];
      accP[0] = __builtin_amdgcn_mfma_f32_16x16x32_bf16(a1f, bp0, accP[0], 0, 0, 0);
      accP[1] = __builtin_amdgcn_mfma_f32_16x16x32_bf16(a1f, bp1, accP[1], 0, 0, 0);
    }
  }

  // cb1 softmax + P1 store: lane (hi,lr): code = 4*hi + r, pos = n0 + wave*32 + tt*16 + lr
  if (MODE == 0 && blockIdx.y == 0) {
    const int hi = lane >> 4;
    const float gv1 = gg1[0];
#pragma unroll
    for (int tt = 0; tt < 2; ++tt) {
      float m = fmaxf(fmaxf(accP[tt][0], accP[tt][1]), fmaxf(accP[tt][2], accP[tt][3]));
      m = fmaxf(m, __shfl_xor(m, 16, 64));
      m = fmaxf(m, __shfl_xor(m, 32, 64));
      float e[4], s = 0.f;
#pragma unroll
      for (int r = 0; r < 4; r++) { e[r] = __expf(accP[tt][r] - m); s += e[r]; }
      s += __shfl_xor(s, 16, 64);
      s += __shfl_xor(s, 32, 64);
      float sc = gv1 / s;
      *(uint64_t*)&P1p[(bHW + n0 + wave * 32 + tt * 16 + lrow) * 16 + 4 * hi] =
          pack4bf(e[0] * sc, e[1] * sc, e[2] * sc, e[3] * sc);
    }
  }

  // epilogue: BN + ReLU, TRANSPOSED store Yt[n][e] (4 e-contiguous per lane -> 8B)
  const int rbase = (lane >> 4) * 4;
  const int col   = lane & 15;
#pragma unroll
  for (int ma = 0; ma < 4; ma++) {
    const int ebase = e0 + wr * 64 + ma * 16 + rbase;
    float sc[4], sh[4];
#pragma unroll
    for (int r = 0; r < 4; r++) { sc[r] = scale[ebase + r]; sh[r] = shift[ebase + r]; }
#pragma unroll
    for (int nb = 0; nb < 4; nb++) {
      const int n = n0 + wc * 64 + nb * 16 + col;
      float y[4];
#pragma unroll
      for (int r = 0; r < 4; r++) {
        float t = acc[ma][nb][r] * sc[r] + sh[r];
        y[r] = t > 0.f ? t : 0.f;
      }
      *(uint64_t*)&Yt[(bHW + n) * 512 + ebase] = pack4bf(y[0], y[1], y[2], y[3]);
    }
  }
}

// -------- vq_fused: cb2/cb3 logits (b128 direct-global) + softmax + recon + X add --------
// Block: 64 positions, 4 waves. Phase 1: A = position rows from X2t/X3t (b128),
// B = CWt rows 16..111 (L2-hot). Phase 2: softmax over lr (xor1..8); P' -> chunked
// LDS [oct16][pos64][8] (conflict-free b128); P1 loaded from P1p. Phase 3: recon
// with direct-global CWc frags, fused out = X + E.
__global__ __launch_bounds__(256) void vq_fused(
    const float* __restrict__ X, const unsigned short* __restrict__ X2t,
    const unsigned short* __restrict__ X3t, const unsigned short* __restrict__ CWt,
    const unsigned short* __restrict__ CWc, const unsigned short* __restrict__ P1p,
    const float* __restrict__ gg2, const float* __restrict__ gg3,
    float* __restrict__ out) {
  const int b  = blockIdx.y;
  const int n0 = blockIdx.x * 64;
  const int tid  = threadIdx.x;
  const int lane = tid & 63;
  const int wv   = tid >> 6;
  const int hi = lane >> 4, lr = lane & 15;
  const size_t bHW = (size_t)b * HW;

  __shared__ __align__(16) unsigned short LDS[8192];   // 16 KB: [oct16][pos64][8]

  const size_t grow = (bHW + n0 + wv * 16 + lr) * 512;
  const unsigned short* p2 = X2t + grow;
  const unsigned short* p3 = X3t + grow;

  f32x4 acc2[2], acc3[4];
  acc2[0] = (f32x4)0.0f; acc2[1] = (f32x4)0.0f;
#pragma unroll
  for (int t = 0; t < 4; t++) acc3[t] = (f32x4)0.0f;

#define LOADX(kt, c2, c3)                         \
  {                                               \
    const int off = (kt) * 32 + hi * 8;           \
    c2 = *(const short8*)&p2[off];                \
    c3 = *(const short8*)&p3[off];                \
  }
#define STEP(kt, c2, c3)                                                                \
  {                                                                                     \
    const int d0 = (kt) * 32 + hi * 8;                                                  \
    short8 bt[6];                                                                       \
    _Pragma("unroll")                                                                   \
    for (int t = 0; t < 6; t++)                                                         \
      bt[t] = *(const short8*)&CWt[(size_t)(16 + t * 16 + lr) * 512 + d0];              \
    acc2[0] = __builtin_amdgcn_mfma_f32_16x16x32_bf16(c2, bt[0], acc2[0], 0, 0, 0);     \
    acc2[1] = __builtin_amdgcn_mfma_f32_16x16x32_bf16(c2, bt[1], acc2[1], 0, 0, 0);     \
    _Pragma("unroll")                                                                   \
    for (int t = 0; t < 4; t++)                                                         \
      acc3[t] = __builtin_amdgcn_mfma_f32_16x16x32_bf16(c3, bt[2 + t], acc3[t], 0, 0, 0); \
  }

  short8 c2A, c3A, c2B, c3B;
  LOADX(0, c2A, c3A);
  for (int kt = 0; kt < 16; kt += 2) {
    LOADX(kt + 1, c2B, c3B);
    STEP(kt, c2A, c3A);
    if (kt + 2 < 16) LOADX(kt + 2, c2A, c3A);
    STEP(kt + 1, c2B, c3B);
  }
#undef LOADX
#undef STEP

  // softmax: lane (hi,lr) reg r holds pos = wv*16+4*hi+r; cb2 code = 16+16t+lr,
  // cb3 code = 48+16t+lr. Reduce over codes = over regs/tiles + lr (xor 1..8).
  // P' chunked store: oct = code>>3, slot = code&7 -> LDS[oct*512 + pos*8 + slot].
  {
    const float gv2 = gg2[0], gv3 = gg3[0];
    const int pbase = (wv * 16 + 4 * hi) * 8 + (lr & 7);
    const int o8 = (lr >> 3) * 512;
    {  // cb2: tiles 1,2 of the concat codebook
      float m = acc2[0][0];
#pragma unroll
      for (int r = 1; r < 4; r++) m = fmaxf(m, acc2[0][r]);
#pragma unroll
      for (int r = 0; r < 4; r++) m = fmaxf(m, acc2[1][r]);
#pragma unroll
      for (int mk = 1; mk <= 8; mk <<= 1) m = fmaxf(m, __shfl_xor(m, mk, 64));
      float e1[4], e2[4], s = 0.f;
#pragma unroll
      for (int r = 0; r < 4; r++) { e1[r] = __expf(acc2[0][r] - m); s += e1[r]; }
#pragma unroll
      for (int r = 0; r < 4; r++) { e2[r] = __expf(acc2[1][r] - m); s += e2[r]; }
#pragma unroll
      for (int mk = 1; mk <= 8; mk <<= 1) s += __shfl_xor(s, mk, 64);
      float sc = gv2 / s;
#pragma unroll
      for (int r = 0; r < 4; r++) {
        LDS[2 * 512 + o8 + pbase + r * 8] = f2bf(e1[r] * sc);
        LDS[4 * 512 + o8 + pbase + r * 8] = f2bf(e2[r] * sc);
      }
    }
    {  // cb3: tiles 3..6
      float m = acc3[0][0];
#pragma unroll
      for (int t = 0; t < 4; t++)
#pragma unroll
        for (int r = 0; r < 4; r++) m = fmaxf(m, acc3[t][r]);
#pragma unroll
      for (int mk = 1; mk <= 8; mk <<= 1) m = fmaxf(m, __shfl_xor(m, mk, 64));
      float e[4][4], s = 0.f;
#pragma unroll
      for (int t = 0; t < 4; t++)
#pragma unroll
        for (int r = 0; r < 4; r++) { e[t][r] = __expf(acc3[t][r] - m); s += e[t][r]; }
#pragma unroll
      for (int mk = 1; mk <= 8; mk <<= 1) s += __shfl_xor(s, mk, 64);
      float sc = gv3 / s;
#pragma unroll
      for (int t = 0; t < 4; t++)
#pragma unroll
        for (int r = 0; r < 4; r++)
          LDS[(2 * (3 + t)) * 512 + o8 + pbase + r * 8] = f2bf(e[t][r] * sc);
    }
    // P1 (codes 0..15) from P1p: thread -> pos=tid&63, cg=tid>>6 (codes 4cg..4cg+3)
    {
      const int pp = tid & 63, cg = tid >> 6;
      uint64_t v = *(const uint64_t*)&P1p[(bHW + n0 + pp) * 16 + cg * 4];
      *(uint64_t*)&LDS[(cg >> 1) * 512 + pp * 8 + (cg & 1) * 4] = v;
    }
    // zero pad codes 112..127 (octs 14,15)
    if (tid < 128) *(short8*)&LDS[7168 + tid * 8] = (short8)0;
  }
  __syncthreads();

  // pf frags: B-operand of recon GEMM (col = pos = ct*16+lr, k = code = s*32+hi*8+j)
  short8 pf[4][4];
#pragma unroll
  for (int ct = 0; ct < 4; ++ct)
#pragma unroll
    for (int s = 0; s < 4; ++s)
      pf[ct][s] = *(const short8*)&LDS[(4 * s + hi) * 512 + (ct * 16 + lr) * 8];

  const float* Xg = X + bHW * DD;
  float* og = out + bHW * DD;

  for (int c = 0; c < 8; ++c) {
    const int dt = c * 4 + wv;
    f32x4 acc[4];
#pragma unroll
    for (int ct = 0; ct < 4; ++ct) acc[ct] = (f32x4)0.0f;
#pragma unroll
    for (int s = 0; s < 4; ++s) {
      short8 af = *(const short8*)&CWc[(size_t)(dt * 16 + lr) * 128 + s * 32 + hi * 8];
#pragma unroll
      for (int ct = 0; ct < 4; ++ct)
        acc[ct] = __builtin_amdgcn_mfma_f32_16x16x32_bf16(af, pf[ct][s], acc[ct], 0, 0, 0);
    }
    const int dgb = dt * 16 + 4 * hi;
#pragma unroll
    for (int ct = 0; ct < 4; ++ct) {
      const int n = n0 + ct * 16 + lr;
#pragma unroll
      for (int r = 0; r < 4; ++r) {
        const size_t a = (size_t)(dgb + r) * HW + n;
        og[a] = Xg[a] + acc[ct][r];
      }
    }
  }
}

extern "C" void kernel_launch(void* const* d_in, const int* in_sizes, int n_in,
                              void* d_out, int out_size, void* d_ws, size_t ws_size,
                              hipStream_t stream) {
  const float* X    = (const float*)d_in[0];
  const float* W1   = (const float*)d_in[1];
  const float* bn1s = (const float*)d_in[2];
  const float* bn1b = (const float*)d_in[3];
  const float* bn1m = (const float*)d_in[4];
  const float* bn1v = (const float*)d_in[5];
  const float* W2   = (const float*)d_in[6];
  const float* bn2s = (const float*)d_in[7];
  const float* bn2b = (const float*)d_in[8];
  const float* bn2m = (const float*)d_in[9];
  const float* bn2v = (const float*)d_in[10];
  const float* cw1  = (const float*)d_in[11];
  const float* cw2  = (const float*)d_in[12];
  const float* cw3  = (const float*)d_in[13];
  const float* g1   = (const float*)d_in[14];
  const float* g2   = (const float*)d_in[15];
  const float* g3   = (const float*)d_in[16];

  // ws (all scratch here; no d_out reuse, no aliasing):
  // W1b 512K | W2b 512K | scales 8K | CWt 112K | CWc 128K | X2t 72M | X3t 72M | P1p 2.3M
  char* ws = (char*)d_ws;
  unsigned short* W1b = (unsigned short*)(ws);
  unsigned short* W2b = (unsigned short*)(ws + 524288);
  float* sc1 = (float*)(ws + 1048576);
  float* sh1 = sc1 + 512;
  float* sc2 = sh1 + 512;
  float* sh2 = sc2 + 512;
  unsigned short* CWt = (unsigned short*)(ws + 1056768);
  unsigned short* CWc = (unsigned short*)(ws + 1171456);
  unsigned short* X2t = (unsigned short*)(ws + 1302528);
  unsigned short* X3t = X2t + (size_t)NBATCH * HW * DD;      // ws + 76800000
  unsigned short* P1p = X3t + (size_t)NBATCH * HW * DD;      // ws + 152297472, 2.36MB

  prep_kernel<<<1024, 256, 0, stream>>>(W1, W2, bn1s, bn1b, bn1m, bn1v,
                                        bn2s, bn2b, bn2m, bn2v,
                                        W1b, W2b, sc1, sh1, sc2, sh2);
  prep_cw<<<256, 256, 0, stream>>>(cw1, cw2, cw3, CWt, CWc);

  dim3 gg(HW / 128, DD / 128, NBATCH);
  gemm_bn<0><<<gg, 256, 0, stream>>>((const void*)X,   W1b, sc1, sh1, CWt, g1, X2t, P1p);
  gemm_bn<1><<<gg, 256, 0, stream>>>((const void*)X2t, W2b, sc2, sh2, CWt, g1, X3t, nullptr);

  dim3 gv(HW / 64, NBATCH);   // (144, 8)
  vq_fused<<<gv, 256, 0, stream>>>(X, X2t, X3t, CWt, CWc, P1p, g2, g3, (float*)d_out);
}

// Round 14
// 423.658 us; speedup vs baseline: 1.0352x; 1.0352x over previous
//
#include <hip/hip_runtime.h>
#include <hip/hip_bf16.h>
#include <stdint.h>

#define DD 512
#define HW 9216
#define NBATCH 8
#define BN_EPS 1e-5f

typedef __attribute__((ext_vector_type(8))) short short8;
typedef __attribute__((ext_vector_type(4))) float f32x4;

__device__ __forceinline__ unsigned short f2bf(float f) {
  union { float f; uint32_t u; } v; v.f = f;
  uint32_t r = v.u + 0x7FFFu + ((v.u >> 16) & 1u);   // RNE
  return (unsigned short)(r >> 16);
}
__device__ __forceinline__ uint64_t pack4bf(float y0, float y1, float y2, float y3) {
  return (uint64_t)f2bf(y0) | ((uint64_t)f2bf(y1) << 16) |
         ((uint64_t)f2bf(y2) << 32) | ((uint64_t)f2bf(y3) << 48);
}

// ---------------- prep: bf16 weights + folded BN ----------------
__global__ void prep_kernel(const float* __restrict__ W1, const float* __restrict__ W2,
                            const float* __restrict__ s1, const float* __restrict__ b1,
                            const float* __restrict__ m1, const float* __restrict__ v1,
                            const float* __restrict__ s2, const float* __restrict__ b2,
                            const float* __restrict__ m2, const float* __restrict__ v2,
                            unsigned short* __restrict__ W1b, unsigned short* __restrict__ W2b,
                            float* __restrict__ sc1, float* __restrict__ sh1,
                            float* __restrict__ sc2, float* __restrict__ sh2) {
  int t = blockIdx.x * 256 + threadIdx.x;
  if (t < DD * DD) { W1b[t] = f2bf(W1[t]); W2b[t] = f2bf(W2[t]); }
  if (t < DD) {
    float a = s1[t] * rsqrtf(v1[t] + BN_EPS);
    sc1[t] = a; sh1[t] = b1[t] - m1[t] * a;
    float c = s2[t] * rsqrtf(v2[t] + BN_EPS);
    sc2[t] = c; sh2[t] = b2[t] - m2[t] * c;
  }
}

// prep codebooks: CWt[112][512] (transposed concat), CWc[512][128] (native concat, 0-pad)
__global__ void prep_cw(const float* __restrict__ cw1, const float* __restrict__ cw2,
                        const float* __restrict__ cw3,
                        unsigned short* __restrict__ CWt, unsigned short* __restrict__ CWc) {
  int t = blockIdx.x * 256 + threadIdx.x;   // 65536 total
  int d = t >> 7, k = t & 127;
  float v = 0.f;
  if (k < 16) v = cw1[d * 16 + k];
  else if (k < 48) v = cw2[d * 32 + (k - 16)];
  else if (k < 112) v = cw3[d * 64 + (k - 48)];
  unsigned short bv = f2bf(v);
  CWc[d * 128 + k] = bv;
  if (k < 112) CWt[k * 512 + d] = bv;
}

// ------- GEMM + BN + ReLU; output TRANSPOSED Yt[n][e] bf16 -------
// MODE 0: input X fp32 [d][n] (scalar-gather B-stage) + fused cb1 logits+softmax
//         -> P1p[n][16] (blockIdx.y==0 blocks only; d is the K dim, fully in-block).
// MODE 1: input X2t bf16 [n][e] (b128 B-stage).
template <int MODE>
__global__ __launch_bounds__(256) void gemm_bn(
    const void* __restrict__ Xin_, const unsigned short* __restrict__ Wb,
    const float* __restrict__ scale, const float* __restrict__ shift,
    const unsigned short* __restrict__ CWt, const float* __restrict__ gg1,
    unsigned short* __restrict__ Yt, unsigned short* __restrict__ P1p) {
  const int b  = blockIdx.z;
  const int e0 = blockIdx.y * 128;
  const int n0 = blockIdx.x * 128;
  const int tid  = threadIdx.x;
  const int lane = tid & 63;
  const int wave = tid >> 6;
  const int wr = wave >> 1, wc = wave & 1;
  const size_t bHW = (size_t)b * HW;

  constexpr int BSTR = (MODE == 0) ? 40 : 32;
  __shared__ __align__(16) unsigned short Alds[128 * 32];
  __shared__ __align__(16) unsigned short Blds[128 * BSTR];

  const float* Xf           = (const float*)Xin_ + bHW * DD;          // MODE 0
  const unsigned short* Xt  = (const unsigned short*)Xin_;            // MODE 1: [g][512]

  f32x4 acc[4][4];
#pragma unroll
  for (int i = 0; i < 4; i++)
#pragma unroll
    for (int j = 0; j < 4; j++) acc[i][j] = (f32x4)0.0f;

  f32x4 accP[2];             // cb1 logits (MODE 0, y==0 only)
  accP[0] = (f32x4)0.0f; accP[1] = (f32x4)0.0f;

  const int arow  = tid >> 1;
  const int ahalf = tid & 1;
  const int bcol  = tid & 127;
  const int bdh   = tid >> 7;

  const int koff = (lane >> 4) * 8;
  const int lrow = lane & 15;

  for (int kt = 0; kt < DD / 32; ++kt) {
    const int d0 = kt * 32;
    __syncthreads();
    {  // stage A: W rows (bf16, contiguous)
      const unsigned short* src = Wb + (size_t)(e0 + arow) * DD + d0 + ahalf * 16;
      short8 v0 = *(const short8*)(src);
      short8 v1 = *(const short8*)(src + 8);
      *(short8*)&Alds[arow * 32 + ahalf * 16]     = v0;
      *(short8*)&Alds[arow * 32 + ahalf * 16 + 8] = v1;
    }
    if (MODE == 0) {  // stage B: transpose-gather X fp32 [d][n] -> Blds[n][k]
      unsigned short* dst = &Blds[bcol * 40 + bdh * 16];
      const float* src = Xf + (size_t)(d0 + bdh * 16) * HW + n0 + bcol;
#pragma unroll
      for (int j = 0; j < 8; j++) {
        uint32_t u0 = f2bf(src[(size_t)(2 * j) * HW]);
        uint32_t u1 = f2bf(src[(size_t)(2 * j + 1) * HW]);
        *(uint32_t*)&dst[2 * j] = u0 | (u1 << 16);
      }
    } else {          // stage B: b128 rows from X2t [g][512]
      const int row = tid >> 1, half = tid & 1;
      short8 v = *(const short8*)&Xt[(bHW + n0 + row) * 512 + d0 + half * 16];
      *(short8*)&Blds[row * 32 + half * 16] = v;
    }
    __syncthreads();

    short8 af[4], bfr[4];
#pragma unroll
    for (int ma = 0; ma < 4; ma++)
      af[ma] = *(const short8*)&Alds[(wr * 64 + ma * 16 + lrow) * 32 + koff];
#pragma unroll
    for (int nb = 0; nb < 4; nb++)
      bfr[nb] = *(const short8*)&Blds[(wc * 64 + nb * 16 + lrow) * BSTR + koff];
#pragma unroll
    for (int ma = 0; ma < 4; ma++)
#pragma unroll
      for (int nb = 0; nb < 4; nb++)
        acc[ma][nb] = __builtin_amdgcn_mfma_f32_16x16x32_bf16(af[ma], bfr[nb], acc[ma][nb], 0, 0, 0);

    if (MODE == 0 && blockIdx.y == 0) {
      // cb1 logits: A = CWt rows 0..15 (codes), B = this wave's 2 pos-tiles.
      short8 a1f = *(const short8*)&CWt[(size_t)lrow * 512 + d0 + koff];
      short8 bp0 = *(const short8*)&Blds[(wave * 32 + lrow) * 40 + koff];
      short8 bp1 = *(const short8*)&Blds[(wave * 32 + 16 + lrow) * 40 + koff];
      accP[0] = __builtin_amdgcn_mfma_f32_16x16x32_bf16(a1f, bp0, accP[0], 0, 0, 0);
      accP[1] = __builtin_amdgcn_mfma_f32_16x16x32_bf16(a1f, bp1, accP[1], 0, 0, 0);
    }
  }

  // cb1 softmax + P1 store: lane (hi,lr): code = 4*hi + r, pos = n0 + wave*32 + tt*16 + lr
  if (MODE == 0 && blockIdx.y == 0) {
    const int hi = lane >> 4;
    const float gv1 = gg1[0];
#pragma unroll
    for (int tt = 0; tt < 2; ++tt) {
      float m = fmaxf(fmaxf(accP[tt][0], accP[tt][1]), fmaxf(accP[tt][2], accP[tt][3]));
      m = fmaxf(m, __shfl_xor(m, 16, 64));
      m = fmaxf(m, __shfl_xor(m, 32, 64));
      float e[4], s = 0.f;
#pragma unroll
      for (int r = 0; r < 4; r++) { e[r] = __expf(accP[tt][r] - m); s += e[r]; }
      s += __shfl_xor(s, 16, 64);
      s += __shfl_xor(s, 32, 64);
      float sc = gv1 / s;
      *(uint64_t*)&P1p[(bHW + n0 + wave * 32 + tt * 16 + lrow) * 16 + 4 * hi] =
          pack4bf(e[0] * sc, e[1] * sc, e[2] * sc, e[3] * sc);
    }
  }

  // epilogue: BN + ReLU, TRANSPOSED store Yt[n][e] (4 e-contiguous per lane -> 8B)
  const int rbase = (lane >> 4) * 4;
  const int col   = lane & 15;
#pragma unroll
  for (int ma = 0; ma < 4; ma++) {
    const int ebase = e0 + wr * 64 + ma * 16 + rbase;
    float sc[4], sh[4];
#pragma unroll
    for (int r = 0; r < 4; r++) { sc[r] = scale[ebase + r]; sh[r] = shift[ebase + r]; }
#pragma unroll
    for (int nb = 0; nb < 4; nb++) {
      const int n = n0 + wc * 64 + nb * 16 + col;
      float y[4];
#pragma unroll
      for (int r = 0; r < 4; r++) {
        float t = acc[ma][nb][r] * sc[r] + sh[r];
        y[r] = t > 0.f ? t : 0.f;
      }
      *(uint64_t*)&Yt[(bHW + n) * 512 + ebase] = pack4bf(y[0], y[1], y[2], y[3]);
    }
  }
}

// -------- vq_fused v2: deep-pipelined fragment loads (fix reg-starved serialization) ----
// __launch_bounds__(256,3): 170-VGPR cap so double-buffered fragments stay in registers.
// Phase 1: X-streams AND CWt fragments double-buffered (issue one full step ahead).
// Phase 3: CWc fragments prefetched one chunk ahead (unroll-by-2, static buffers).
__global__ __launch_bounds__(256, 3) void vq_fused(
    const float* __restrict__ X, const unsigned short* __restrict__ X2t,
    const unsigned short* __restrict__ X3t, const unsigned short* __restrict__ CWt,
    const unsigned short* __restrict__ CWc, const unsigned short* __restrict__ P1p,
    const float* __restrict__ gg2, const float* __restrict__ gg3,
    float* __restrict__ out) {
  const int b  = blockIdx.y;
  const int n0 = blockIdx.x * 64;
  const int tid  = threadIdx.x;
  const int lane = tid & 63;
  const int wv   = tid >> 6;
  const int hi = lane >> 4, lr = lane & 15;
  const size_t bHW = (size_t)b * HW;

  __shared__ __align__(16) unsigned short LDS[8192];   // 16 KB: [oct16][pos64][8]

  const size_t grow = (bHW + n0 + wv * 16 + lr) * 512;
  const unsigned short* p2 = X2t + grow;
  const unsigned short* p3 = X3t + grow;

  f32x4 acc2[2], acc3[4];
  acc2[0] = (f32x4)0.0f; acc2[1] = (f32x4)0.0f;
#pragma unroll
  for (int t = 0; t < 4; t++) acc3[t] = (f32x4)0.0f;

#define LOADX(kt, cx2, cx3)                       \
  {                                               \
    const int off = (kt) * 32 + hi * 8;           \
    cx2 = *(const short8*)&p2[off];               \
    cx3 = *(const short8*)&p3[off];               \
  }
#define LOADB(kt, bt)                                                       \
  {                                                                         \
    const int d0 = (kt) * 32 + hi * 8;                                      \
    _Pragma("unroll")                                                       \
    for (int t = 0; t < 6; t++)                                             \
      bt[t] = *(const short8*)&CWt[(size_t)(16 + t * 16 + lr) * 512 + d0];  \
  }
#define STEPM(cx2, cx3, bt)                                                             \
  {                                                                                     \
    acc2[0] = __builtin_amdgcn_mfma_f32_16x16x32_bf16(cx2, bt[0], acc2[0], 0, 0, 0);    \
    acc2[1] = __builtin_amdgcn_mfma_f32_16x16x32_bf16(cx2, bt[1], acc2[1], 0, 0, 0);    \
    _Pragma("unroll")                                                                   \
    for (int t = 0; t < 4; t++)                                                         \
      acc3[t] = __builtin_amdgcn_mfma_f32_16x16x32_bf16(cx3, bt[2 + t], acc3[t], 0, 0, 0); \
  }

  {
    short8 c2A, c3A, c2B, c3B;
    short8 btA[6], btB[6];
    LOADX(0, c2A, c3A);
    LOADB(0, btA);
    for (int kt = 0; kt < 16; kt += 2) {
      LOADX(kt + 1, c2B, c3B);
      LOADB(kt + 1, btB);
      STEPM(c2A, c3A, btA);
      if (kt + 2 < 16) { LOADX(kt + 2, c2A, c3A); LOADB(kt + 2, btA); }
      STEPM(c2B, c3B, btB);
    }
  }
#undef LOADX
#undef LOADB
#undef STEPM

  // softmax: lane (hi,lr) reg r holds pos = wv*16+4*hi+r; cb2 code = 16+16t+lr,
  // cb3 code = 48+16t+lr. Reduce over codes = over regs/tiles + lr (xor 1..8).
  // P' chunked store: oct = code>>3, slot = code&7 -> LDS[oct*512 + pos*8 + slot].
  {
    const float gv2 = gg2[0], gv3 = gg3[0];
    const int pbase = (wv * 16 + 4 * hi) * 8 + (lr & 7);
    const int o8 = (lr >> 3) * 512;
    {  // cb2: tiles 1,2 of the concat codebook
      float m = acc2[0][0];
#pragma unroll
      for (int r = 1; r < 4; r++) m = fmaxf(m, acc2[0][r]);
#pragma unroll
      for (int r = 0; r < 4; r++) m = fmaxf(m, acc2[1][r]);
#pragma unroll
      for (int mk = 1; mk <= 8; mk <<= 1) m = fmaxf(m, __shfl_xor(m, mk, 64));
      float e1[4], e2[4], s = 0.f;
#pragma unroll
      for (int r = 0; r < 4; r++) { e1[r] = __expf(acc2[0][r] - m); s += e1[r]; }
#pragma unroll
      for (int r = 0; r < 4; r++) { e2[r] = __expf(acc2[1][r] - m); s += e2[r]; }
#pragma unroll
      for (int mk = 1; mk <= 8; mk <<= 1) s += __shfl_xor(s, mk, 64);
      float sc = gv2 / s;
#pragma unroll
      for (int r = 0; r < 4; r++) {
        LDS[2 * 512 + o8 + pbase + r * 8] = f2bf(e1[r] * sc);
        LDS[4 * 512 + o8 + pbase + r * 8] = f2bf(e2[r] * sc);
      }
    }
    {  // cb3: tiles 3..6
      float m = acc3[0][0];
#pragma unroll
      for (int t = 0; t < 4; t++)
#pragma unroll
        for (int r = 0; r < 4; r++) m = fmaxf(m, acc3[t][r]);
#pragma unroll
      for (int mk = 1; mk <= 8; mk <<= 1) m = fmaxf(m, __shfl_xor(m, mk, 64));
      float e[4][4], s = 0.f;
#pragma unroll
      for (int t = 0; t < 4; t++)
#pragma unroll
        for (int r = 0; r < 4; r++) { e[t][r] = __expf(acc3[t][r] - m); s += e[t][r]; }
#pragma unroll
      for (int mk = 1; mk <= 8; mk <<= 1) s += __shfl_xor(s, mk, 64);
      float sc = gv3 / s;
#pragma unroll
      for (int t = 0; t < 4; t++)
#pragma unroll
        for (int r = 0; r < 4; r++)
          LDS[(2 * (3 + t)) * 512 + o8 + pbase + r * 8] = f2bf(e[t][r] * sc);
    }
    // P1 (codes 0..15) from P1p: thread -> pos=tid&63, cg=tid>>6 (codes 4cg..4cg+3)
    {
      const int pp = tid & 63, cg = tid >> 6;
      uint64_t v = *(const uint64_t*)&P1p[(bHW + n0 + pp) * 16 + cg * 4];
      *(uint64_t*)&LDS[(cg >> 1) * 512 + pp * 8 + (cg & 1) * 4] = v;
    }
    // zero pad codes 112..127 (octs 14,15)
    if (tid < 128) *(short8*)&LDS[7168 + tid * 8] = (short8)0;
  }
  __syncthreads();

  // pf frags: B-operand of recon GEMM (col = pos = ct*16+lr, k = code = s*32+hi*8+j)
  short8 pf[4][4];
#pragma unroll
  for (int ct = 0; ct < 4; ++ct)
#pragma unroll
    for (int s = 0; s < 4; ++s)
      pf[ct][s] = *(const short8*)&LDS[(4 * s + hi) * 512 + (ct * 16 + lr) * 8];

  const float* Xg = X + bHW * DD;
  float* og = out + bHW * DD;

#define LOADC(c, af)                                                                    \
  {                                                                                     \
    const int dt = (c) * 4 + wv;                                                        \
    _Pragma("unroll")                                                                   \
    for (int s = 0; s < 4; s++)                                                         \
      af[s] = *(const short8*)&CWc[(size_t)(dt * 16 + lr) * 128 + s * 32 + hi * 8];     \
  }
#define COMPC(c, af)                                                                    \
  {                                                                                     \
    f32x4 acc[4];                                                                       \
    _Pragma("unroll")                                                                   \
    for (int ct = 0; ct < 4; ++ct) acc[ct] = (f32x4)0.0f;                               \
    _Pragma("unroll")                                                                   \
    for (int s = 0; s < 4; ++s) {                                                       \
      _Pragma("unroll")                                                                 \
      for (int ct = 0; ct < 4; ++ct)                                                    \
        acc[ct] = __builtin_amdgcn_mfma_f32_16x16x32_bf16(af[s], pf[ct][s], acc[ct], 0, 0, 0); \
    }                                                                                   \
    const int dgb = ((c) * 4 + wv) * 16 + 4 * hi;                                       \
    _Pragma("unroll")                                                                   \
    for (int ct = 0; ct < 4; ++ct) {                                                    \
      const int n = n0 + ct * 16 + lr;                                                  \
      _Pragma("unroll")                                                                 \
      for (int r = 0; r < 4; ++r) {                                                     \
        const size_t a = (size_t)(dgb + r) * HW + n;                                    \
        og[a] = Xg[a] + acc[ct][r];                                                     \
      }                                                                                 \
    }                                                                                   \
  }

  {
    short8 afA[4], afB[4];
    LOADC(0, afA);
#pragma unroll
    for (int cc = 0; cc < 4; ++cc) {
      LOADC(2 * cc + 1, afB);
      COMPC(2 * cc, afA);
      if (cc < 3) LOADC(2 * cc + 2, afA);
      COMPC(2 * cc + 1, afB);
    }
  }
#undef LOADC
#undef COMPC
}

extern "C" void kernel_launch(void* const* d_in, const int* in_sizes, int n_in,
                              void* d_out, int out_size, void* d_ws, size_t ws_size,
                              hipStream_t stream) {
  const float* X    = (const float*)d_in[0];
  const float* W1   = (const float*)d_in[1];
  const float* bn1s = (const float*)d_in[2];
  const float* bn1b = (const float*)d_in[3];
  const float* bn1m = (const float*)d_in[4];
  const float* bn1v = (const float*)d_in[5];
  const float* W2   = (const float*)d_in[6];
  const float* bn2s = (const float*)d_in[7];
  const float* bn2b = (const float*)d_in[8];
  const float* bn2m = (const float*)d_in[9];
  const float* bn2v = (const float*)d_in[10];
  const float* cw1  = (const float*)d_in[11];
  const float* cw2  = (const float*)d_in[12];
  const float* cw3  = (const float*)d_in[13];
  const float* g1   = (const float*)d_in[14];
  const float* g2   = (const float*)d_in[15];
  const float* g3   = (const float*)d_in[16];

  // ws (all scratch here; no d_out reuse, no aliasing):
  // W1b 512K | W2b 512K | scales 8K | CWt 112K | CWc 128K | X2t 72M | X3t 72M | P1p 2.3M
  char* ws = (char*)d_ws;
  unsigned short* W1b = (unsigned short*)(ws);
  unsigned short* W2b = (unsigned short*)(ws + 524288);
  float* sc1 = (float*)(ws + 1048576);
  float* sh1 = sc1 + 512;
  float* sc2 = sh1 + 512;
  float* sh2 = sc2 + 512;
  unsigned short* CWt = (unsigned short*)(ws + 1056768);
  unsigned short* CWc = (unsigned short*)(ws + 1171456);
  unsigned short* X2t = (unsigned short*)(ws + 1302528);
  unsigned short* X3t = X2t + (size_t)NBATCH * HW * DD;      // ws + 76800000
  unsigned short* P1p = X3t + (size_t)NBATCH * HW * DD;      // ws + 152297472, 2.36MB

  prep_kernel<<<1024, 256, 0, stream>>>(W1, W2, bn1s, bn1b, bn1m, bn1v,
                                        bn2s, bn2b, bn2m, bn2v,
                                        W1b, W2b, sc1, sh1, sc2, sh2);
  prep_cw<<<256, 256, 0, stream>>>(cw1, cw2, cw3, CWt, CWc);

  dim3 gg(HW / 128, DD / 128, NBATCH);
  gemm_bn<0><<<gg, 256, 0, stream>>>((const void*)X,   W1b, sc1, sh1, CWt, g1, X2t, P1p);
  gemm_bn<1><<<gg, 256, 0, stream>>>((const void*)X2t, W2b, sc2, sh2, CWt, g1, X3t, nullptr);

  dim3 gv(HW / 64, NBATCH);   // (144, 8)
  vq_fused<<<gv, 256, 0, stream>>>(X, X2t, X3t, CWt, CWc, P1p, g2, g3, (float*)d_out);
}